// Round 1
// baseline (337.856 us; speedup 1.0000x reference)
//
#include <hip/hip_runtime.h>

typedef __attribute__((ext_vector_type(8))) short short8;
typedef __attribute__((ext_vector_type(4))) float f32x4;

#define N_TOK   16384
#define HDIM    1024
#define OUT_OFF 16777216   // 16384*1024
#define M1ROWS  26216      // 2*(2097+11011)
#define M2ROWS  22022      // 2*11011
#define L2ROW0  4194       // 2*2097

__device__ __forceinline__ unsigned short f2bf(float f) {
  unsigned int u = __float_as_uint(f);
  u += 0x7FFFu + ((u >> 16) & 1u);
  return (unsigned short)(u >> 16);
}

// gathered-row index -> (tensor, rank)
__device__ __forceinline__ void rowmap(int r, int& is_v, int& rank) {
  if (r < 2097)       { is_v = 0; rank = 3276 + r; }
  else if (r < 4194)  { is_v = 1; rank = 1179 + r; }
  else if (r < 15205) { is_v = 0; rank = 1179 + r; }
  else                { is_v = 1; rank = r - 9832; }
}

// ---- stable descending rank: count[i] = #{j : imp[j]>imp[i] or (== and j<i)} ----
__global__ __launch_bounds__(256) void rank_count(const float* __restrict__ imp,
                                                  int* __restrict__ counts) {
  __shared__ float sj[2048];
  const int i = blockIdx.x * 256 + threadIdx.x;
  const int jbase = blockIdx.y * 2048;
  const float vi = imp[i];
  for (int s = threadIdx.x; s < 2048; s += 256) sj[s] = imp[jbase + s];
  __syncthreads();
  int cnt = 0;
  #pragma unroll 8
  for (int s = 0; s < 2048; ++s) {
    float vj = sj[s];
    bool gt = vj > vi;
    bool eq = (vj == vi) && ((jbase + s) < i);
    cnt += (gt || eq) ? 1 : 0;
  }
  atomicAdd(&counts[i], cnt);
}

__global__ __launch_bounds__(256) void scatter_order(const int* __restrict__ counts,
                                                     int* __restrict__ order) {
  int i = blockIdx.x * 256 + threadIdx.x;
  order[counts[i]] = i;
}

// ---- weight convert: dst[N][K] bf16 (transposed, zero-padded) from src[Ksrc][Nsrc] f32 ----
__global__ __launch_bounds__(256) void wconv(unsigned short* __restrict__ dst,
                                             const float* __restrict__ src,
                                             int Nd, int Kd, int Nsrc, int Ksrc) {
  int idx = blockIdx.x * 256 + threadIdx.x;
  if (idx >= Nd * Kd) return;
  int n = idx / Kd, k = idx % Kd;
  float v = (n < Nsrc && k < Ksrc) ? src[k * Nsrc + n] : 0.f;
  dst[idx] = f2bf(v);
}

// ---- gather level>=1 rows into bf16 X ----
__global__ __launch_bounds__(256) void gather_rows(unsigned short* __restrict__ X,
                                                   const float* __restrict__ keys,
                                                   const float* __restrict__ values,
                                                   const int* __restrict__ order) {
  int r = blockIdx.x;
  int is_v, rank; rowmap(r, is_v, rank);
  int token = order[rank];
  const float* src = (is_v ? values : keys) + (size_t)token * HDIM;
  int c = threadIdx.x * 4;
  float4 f = *reinterpret_cast<const float4*>(src + c);
  ushort4 h;
  h.x = f2bf(f.x); h.y = f2bf(f.y); h.z = f2bf(f.z); h.w = f2bf(f.w);
  *reinterpret_cast<ushort4*>(X + (size_t)r * HDIM + c) = h;
}

// ---- level 0: exact f32 passthrough ----
__global__ __launch_bounds__(256) void copy_level0(float* __restrict__ out,
                                                   const float* __restrict__ keys,
                                                   const float* __restrict__ values,
                                                   const int* __restrict__ order) {
  int b = blockIdx.x;
  int is_v = b & 1, rank = b >> 1;
  int token = order[rank];
  const float* src = (is_v ? values : keys) + (size_t)token * HDIM;
  float* dst = out + (is_v ? OUT_OFF : 0) + (size_t)token * HDIM;
  int c = threadIdx.x * 4;
  *reinterpret_cast<float4*>(dst + c) = *reinterpret_cast<const float4*>(src + c);
}

#define GLDS16(g, l) __builtin_amdgcn_global_load_lds( \
    (const __attribute__((address_space(1))) void*)(g), \
    (__attribute__((address_space(3))) void*)(l), 16, 0, 0)

// ---- tiled bf16 GEMM: C = relu(A @ B + bias); B given transposed [N][K] ----
// MODE 0: store bf16 to Cbf (ldc). MODE 1: scatter f32 to outf via rowmap/order.
template<int MODE>
__global__ __launch_bounds__(256) void gemm_bias_relu(
    const unsigned short* __restrict__ A, int M, int K,
    const unsigned short* __restrict__ Bt, int N,
    const float* __restrict__ bias, int Nbias,
    unsigned short* __restrict__ Cbf, int ldc,
    float* __restrict__ outf, const int* __restrict__ order) {
  __shared__ __align__(16) unsigned short As[128 * 32];
  __shared__ __align__(16) unsigned short Bs[128 * 32];
  const int tid = threadIdx.x;
  const int wave = tid >> 6, lane = tid & 63;
  const int row0 = blockIdx.x * 128, col0 = blockIdx.y * 128;
  const int lrow = lane >> 2, lk = (lane & 3) * 8;
  const int wr = (wave >> 1) * 64, wc = (wave & 1) * 64;

  // staging: 8 segments of 16 rows; wave handles segs {2w, 2w+1} for A and B
  const int s0 = wave * 2, s1 = wave * 2 + 1;
  int ar0 = row0 + s0 * 16 + lrow; if (ar0 >= M) ar0 = 0;
  int ar1 = row0 + s1 * 16 + lrow; if (ar1 >= M) ar1 = 0;
  int br0 = col0 + s0 * 16 + lrow; if (br0 >= N) br0 = 0;
  int br1 = col0 + s1 * 16 + lrow; if (br1 >= N) br1 = 0;
  const unsigned short* ap0 = A + (size_t)ar0 * K + lk;
  const unsigned short* ap1 = A + (size_t)ar1 * K + lk;
  const unsigned short* bp0 = Bt + (size_t)br0 * K + lk;
  const unsigned short* bp1 = Bt + (size_t)br1 * K + lk;

  f32x4 acc[4][4] = {};
  const int fr = lane & 15, fk = (lane >> 4) * 8;

  for (int k0 = 0; k0 < K; k0 += 32) {
    GLDS16(ap0 + k0, As + s0 * 512);
    GLDS16(ap1 + k0, As + s1 * 512);
    GLDS16(bp0 + k0, Bs + s0 * 512);
    GLDS16(bp1 + k0, Bs + s1 * 512);
    __syncthreads();
    short8 af[4], bfv[4];
    #pragma unroll
    for (int m = 0; m < 4; ++m)
      af[m] = *reinterpret_cast<const short8*>(As + (wr + m * 16 + fr) * 32 + fk);
    #pragma unroll
    for (int n = 0; n < 4; ++n)
      bfv[n] = *reinterpret_cast<const short8*>(Bs + (wc + n * 16 + fr) * 32 + fk);
    #pragma unroll
    for (int m = 0; m < 4; ++m)
      #pragma unroll
      for (int n = 0; n < 4; ++n)
        acc[m][n] = __builtin_amdgcn_mfma_f32_16x16x32_bf16(af[m], bfv[n], acc[m][n], 0, 0, 0);
    __syncthreads();
  }

  const int orow = (lane >> 4) * 4;
  const int ocol = lane & 15;
  #pragma unroll
  for (int m = 0; m < 4; ++m) {
    #pragma unroll
    for (int n = 0; n < 4; ++n) {
      #pragma unroll
      for (int j = 0; j < 4; ++j) {
        int r = row0 + wr + m * 16 + orow + j;
        int c = col0 + wc + n * 16 + ocol;
        if (r < M && c < N) {
          float v = acc[m][n][j] + (c < Nbias ? bias[c] : 0.f);
          v = fmaxf(v, 0.f);
          if (MODE == 0) {
            Cbf[(size_t)r * ldc + c] = f2bf(v);
          } else {
            int iv, rk; rowmap(r, iv, rk);
            int token = order[rk];
            outf[(size_t)(iv ? OUT_OFF : 0) + (size_t)token * HDIM + c] = v;
          }
        }
      }
    }
  }
}

extern "C" void kernel_launch(void* const* d_in, const int* in_sizes, int n_in,
                              void* d_out, int out_size, void* d_ws, size_t ws_size,
                              hipStream_t stream) {
  const float* keys   = (const float*)d_in[0];
  const float* values = (const float*)d_in[1];
  const float* imp    = (const float*)d_in[2];
  const float* We0    = (const float*)d_in[3];
  const float* be0    = (const float*)d_in[4];
  const float* We1    = (const float*)d_in[5];
  const float* be1    = (const float*)d_in[6];
  const float* Wd0    = (const float*)d_in[7];
  const float* bd0    = (const float*)d_in[8];
  const float* Wd1    = (const float*)d_in[9];
  const float* bd1    = (const float*)d_in[10];

  char* ws = (char*)d_ws;
  int* counts           = (int*)(ws);                    // 64 KB
  int* order            = (int*)(ws + 65536);            // 64 KB
  unsigned short* We0T  = (unsigned short*)(ws + 131072);   // [512][1024]
  unsigned short* We1T  = (unsigned short*)(ws + 1179648);  // [224][512]
  unsigned short* Wd1T  = (unsigned short*)(ws + 1409024);  // [512][224]
  unsigned short* Wd0T  = (unsigned short*)(ws + 1638400);  // [1024][512]
  unsigned short* Y     = (unsigned short*)(ws + 2686976);  // [26216][512]
  unsigned short* Z     = (unsigned short*)(ws + 29532160); // [22022][224]
  // X (gathered bf16 inputs) lives in d_out; consumed by GEMM1 before any d_out write.
  unsigned short* X = (unsigned short*)d_out;
  float* outf = (float*)d_out;

  hipMemsetAsync(counts, 0, 65536, stream);
  rank_count<<<dim3(64, 8), 256, 0, stream>>>(imp, counts);
  scatter_order<<<64, 256, 0, stream>>>(counts, order);

  wconv<<<2048, 256, 0, stream>>>(We0T, We0, 512, 1024, 512, 1024);
  wconv<<<448,  256, 0, stream>>>(We1T, We1, 224, 512, 204, 512);
  wconv<<<448,  256, 0, stream>>>(Wd1T, Wd1, 512, 224, 512, 204);
  wconv<<<2048, 256, 0, stream>>>(Wd0T, Wd0, 1024, 512, 1024, 512);

  gather_rows<<<M1ROWS, 256, 0, stream>>>(X, keys, values, order);

  // GEMM1: Y = relu(X @ We0 + be0)   [26216 x 1024] x [1024 x 512]
  gemm_bias_relu<0><<<dim3(205, 4), 256, 0, stream>>>(
      X, M1ROWS, 1024, We0T, 512, be0, 512, Y, 512, nullptr, nullptr);

  // level-0 exact copies (after X consumed)
  copy_level0<<<6552, 256, 0, stream>>>(outf, keys, values, order);

  // GEMM2a: Z = relu(Y_l2 @ We1 + be1)   [22022 x 512] x [512 x 224(pad)]
  gemm_bias_relu<0><<<dim3(173, 2), 256, 0, stream>>>(
      Y + (size_t)L2ROW0 * 512, M2ROWS, 512, We1T, 224, be1, 204, Z, 224, nullptr, nullptr);

  // GEMM2b: Y_l2 = relu(Z @ Wd1 + bd1)   [22022 x 224] x [224 x 512]
  gemm_bias_relu<0><<<dim3(173, 4), 256, 0, stream>>>(
      Z, M2ROWS, 224, Wd1T, 512, bd1, 512, Y + (size_t)L2ROW0 * 512, 512, nullptr, nullptr);

  // GEMM3: out = relu(Y @ Wd0 + bd0), scattered f32  [26216 x 512] x [512 x 1024]
  gemm_bias_relu<1><<<dim3(205, 8), 256, 0, stream>>>(
      Y, M1ROWS, 512, Wd0T, 1024, bd0, 1024, nullptr, 0, outf, order);
}

// Round 2
// 330.870 us; speedup vs baseline: 1.0211x; 1.0211x over previous
//
#include <hip/hip_runtime.h>

typedef __attribute__((ext_vector_type(8))) short short8;
typedef __attribute__((ext_vector_type(4))) float f32x4;

#define N_TOK   16384
#define HDIM    1024
#define OUT_OFF 16777216   // 16384*1024
#define M1ROWS  26216      // 2*(2097+11011)
#define M2ROWS  22022      // 2*11011
#define L2ROW0  4194       // 2*2097

__device__ __forceinline__ unsigned short f2bf(float f) {
  unsigned int u = __float_as_uint(f);
  u += 0x7FFFu + ((u >> 16) & 1u);
  return (unsigned short)(u >> 16);
}

// gathered-row index -> (tensor, rank)
__device__ __forceinline__ void rowmap(int r, int& is_v, int& rank) {
  if (r < 2097)       { is_v = 0; rank = 3276 + r; }
  else if (r < 4194)  { is_v = 1; rank = 1179 + r; }
  else if (r < 15205) { is_v = 0; rank = 1179 + r; }
  else                { is_v = 1; rank = r - 9832; }
}

// ---- stable descending rank: count[i] = #{j : imp[j]>imp[i] or (== and j<i)} ----
__global__ __launch_bounds__(256) void rank_count(const float* __restrict__ imp,
                                                  int* __restrict__ counts) {
  __shared__ float sj[2048];
  const int i = blockIdx.x * 256 + threadIdx.x;
  const int jbase = blockIdx.y * 2048;
  const float vi = imp[i];
  for (int s = threadIdx.x; s < 2048; s += 256) sj[s] = imp[jbase + s];
  __syncthreads();
  int cnt = 0;
  #pragma unroll 8
  for (int s = 0; s < 2048; ++s) {
    float vj = sj[s];
    bool gt = vj > vi;
    bool eq = (vj == vi) && ((jbase + s) < i);
    cnt += (gt || eq) ? 1 : 0;
  }
  atomicAdd(&counts[i], cnt);
}

__global__ __launch_bounds__(256) void scatter_order(const int* __restrict__ counts,
                                                     int* __restrict__ order) {
  int i = blockIdx.x * 256 + threadIdx.x;
  order[counts[i]] = i;
}

// ---- weight convert: dst[N][K] bf16 (transposed, zero-padded) from src[Ksrc][Nsrc] f32 ----
__global__ __launch_bounds__(256) void wconv(unsigned short* __restrict__ dst,
                                             const float* __restrict__ src,
                                             int Nd, int Kd, int Nsrc, int Ksrc) {
  int idx = blockIdx.x * 256 + threadIdx.x;
  if (idx >= Nd * Kd) return;
  int n = idx / Kd, k = idx % Kd;
  float v = (n < Nsrc && k < Ksrc) ? src[k * Nsrc + n] : 0.f;
  dst[idx] = f2bf(v);
}

// ---- gather level>=1 rows into bf16 X ----
__global__ __launch_bounds__(256) void gather_rows(unsigned short* __restrict__ X,
                                                   const float* __restrict__ keys,
                                                   const float* __restrict__ values,
                                                   const int* __restrict__ order) {
  int r = blockIdx.x;
  int is_v, rank; rowmap(r, is_v, rank);
  int token = order[rank];
  const float* src = (is_v ? values : keys) + (size_t)token * HDIM;
  int c = threadIdx.x * 4;
  float4 f = *reinterpret_cast<const float4*>(src + c);
  ushort4 h;
  h.x = f2bf(f.x); h.y = f2bf(f.y); h.z = f2bf(f.z); h.w = f2bf(f.w);
  *reinterpret_cast<ushort4*>(X + (size_t)r * HDIM + c) = h;
}

// ---- level 0: exact f32 passthrough ----
__global__ __launch_bounds__(256) void copy_level0(float* __restrict__ out,
                                                   const float* __restrict__ keys,
                                                   const float* __restrict__ values,
                                                   const int* __restrict__ order) {
  int b = blockIdx.x;
  int is_v = b & 1, rank = b >> 1;
  int token = order[rank];
  const float* src = (is_v ? values : keys) + (size_t)token * HDIM;
  float* dst = out + (is_v ? OUT_OFF : 0) + (size_t)token * HDIM;
  int c = threadIdx.x * 4;
  *reinterpret_cast<float4*>(dst + c) = *reinterpret_cast<const float4*>(src + c);
}

#define GLDS16(g, l) __builtin_amdgcn_global_load_lds( \
    (const __attribute__((address_space(1))) void*)(g), \
    (__attribute__((address_space(3))) void*)(l), 16, 0, 0)

// ---- tiled bf16 GEMM: C = relu(A @ B + bias); B given transposed [N][K] ----
// Double-buffered LDS (2-phase prefetch) + XOR-swizzled LDS layout:
//   LDS slot (row, s) holds global 16B-chunk c = s ^ ((row>>1)&3).
//   Staging keeps LDS linear (global_load_lds) and pre-swizzles the SOURCE;
//   reads apply the same XOR. 16-lane fragment reads then hit all 8 slots
//   2-way (free) instead of 2 slots 8-way.
// MODE 0: store bf16 to Cbf (ldc). MODE 1: scatter f32 to outf via rowmap/order.
template<int MODE>
__global__ __launch_bounds__(256) void gemm_bias_relu(
    const unsigned short* __restrict__ A, int M, int K,
    const unsigned short* __restrict__ Bt, int N,
    const float* __restrict__ bias, int Nbias,
    unsigned short* __restrict__ Cbf, int ldc,
    float* __restrict__ outf, const int* __restrict__ order) {
  __shared__ __align__(16) unsigned short As[2][128 * 32];
  __shared__ __align__(16) unsigned short Bs[2][128 * 32];
  const int tid = threadIdx.x;
  const int wave = tid >> 6, lane = tid & 63;
  const int row0 = blockIdx.x * 128, col0 = blockIdx.y * 128;
  const int lrow = lane >> 2;
  // source chunk for linear LDS slot (lane&3) of row (lane>>2):
  const int lk = (((lane & 3) ^ ((lane >> 3) & 3)) << 3);
  const int wr = (wave >> 1) * 64, wc = (wave & 1) * 64;

  // staging: 8 segments of 16 rows; wave handles segs {2w, 2w+1} for A and B
  const int s0 = wave * 2, s1 = wave * 2 + 1;
  int ar0 = row0 + s0 * 16 + lrow; if (ar0 >= M) ar0 = 0;
  int ar1 = row0 + s1 * 16 + lrow; if (ar1 >= M) ar1 = 0;
  int br0 = col0 + s0 * 16 + lrow; if (br0 >= N) br0 = 0;
  int br1 = col0 + s1 * 16 + lrow; if (br1 >= N) br1 = 0;
  const unsigned short* ap0 = A + (size_t)ar0 * K + lk;
  const unsigned short* ap1 = A + (size_t)ar1 * K + lk;
  const unsigned short* bp0 = Bt + (size_t)br0 * K + lk;
  const unsigned short* bp1 = Bt + (size_t)br1 * K + lk;

  f32x4 acc[4][4] = {};
  const int fr = lane & 15;
  // read-side swizzle: chunk q=(lane>>4) of row (…+fr) lives at slot q^((fr>>1)&3)
  const int qoff = (((lane >> 4) ^ ((fr >> 1) & 3)) << 3);

  const int nt = K >> 5;
  // prologue: stage tile 0 into buf 0
  GLDS16(ap0, As[0] + s0 * 512);
  GLDS16(ap1, As[0] + s1 * 512);
  GLDS16(bp0, Bs[0] + s0 * 512);
  GLDS16(bp1, Bs[0] + s1 * 512);
  __syncthreads();

  int cur = 0;
  for (int t = 0; t < nt; ++t) {
    if (t + 1 < nt) {               // issue next-tile loads FIRST (overlap)
      const int k1 = (t + 1) << 5;
      GLDS16(ap0 + k1, As[cur ^ 1] + s0 * 512);
      GLDS16(ap1 + k1, As[cur ^ 1] + s1 * 512);
      GLDS16(bp0 + k1, Bs[cur ^ 1] + s0 * 512);
      GLDS16(bp1 + k1, Bs[cur ^ 1] + s1 * 512);
    }
    const unsigned short* as = As[cur];
    const unsigned short* bs = Bs[cur];
    short8 af[4], bfv[4];
    #pragma unroll
    for (int m = 0; m < 4; ++m)
      af[m] = *reinterpret_cast<const short8*>(as + (wr + m * 16 + fr) * 32 + qoff);
    #pragma unroll
    for (int n = 0; n < 4; ++n)
      bfv[n] = *reinterpret_cast<const short8*>(bs + (wc + n * 16 + fr) * 32 + qoff);
    #pragma unroll
    for (int m = 0; m < 4; ++m)
      #pragma unroll
      for (int n = 0; n < 4; ++n)
        acc[m][n] = __builtin_amdgcn_mfma_f32_16x16x32_bf16(af[m], bfv[n], acc[m][n], 0, 0, 0);
    __syncthreads();                // drains vmcnt (next tile ready) + lgkm
    cur ^= 1;
  }

  const int orow = (lane >> 4) * 4;
  const int ocol = lane & 15;
  #pragma unroll
  for (int m = 0; m < 4; ++m) {
    #pragma unroll
    for (int n = 0; n < 4; ++n) {
      #pragma unroll
      for (int j = 0; j < 4; ++j) {
        int r = row0 + wr + m * 16 + orow + j;
        int c = col0 + wc + n * 16 + ocol;
        if (r < M && c < N) {
          float v = acc[m][n][j] + (c < Nbias ? bias[c] : 0.f);
          v = fmaxf(v, 0.f);
          if (MODE == 0) {
            Cbf[(size_t)r * ldc + c] = f2bf(v);
          } else {
            int iv, rk; rowmap(r, iv, rk);
            int token = order[rk];
            outf[(size_t)(iv ? OUT_OFF : 0) + (size_t)token * HDIM + c] = v;
          }
        }
      }
    }
  }
}

extern "C" void kernel_launch(void* const* d_in, const int* in_sizes, int n_in,
                              void* d_out, int out_size, void* d_ws, size_t ws_size,
                              hipStream_t stream) {
  const float* keys   = (const float*)d_in[0];
  const float* values = (const float*)d_in[1];
  const float* imp    = (const float*)d_in[2];
  const float* We0    = (const float*)d_in[3];
  const float* be0    = (const float*)d_in[4];
  const float* We1    = (const float*)d_in[5];
  const float* be1    = (const float*)d_in[6];
  const float* Wd0    = (const float*)d_in[7];
  const float* bd0    = (const float*)d_in[8];
  const float* Wd1    = (const float*)d_in[9];
  const float* bd1    = (const float*)d_in[10];

  char* ws = (char*)d_ws;
  int* counts           = (int*)(ws);                    // 64 KB
  int* order            = (int*)(ws + 65536);            // 64 KB
  unsigned short* We0T  = (unsigned short*)(ws + 131072);   // [512][1024]
  unsigned short* We1T  = (unsigned short*)(ws + 1179648);  // [224][512]
  unsigned short* Wd1T  = (unsigned short*)(ws + 1409024);  // [512][224]
  unsigned short* Wd0T  = (unsigned short*)(ws + 1638400);  // [1024][512]
  unsigned short* Y     = (unsigned short*)(ws + 2686976);  // [26216][512]
  unsigned short* Z     = (unsigned short*)(ws + 29532160); // [22022][224]
  // X (gathered bf16 inputs) lives in d_out; consumed by GEMM1 before any d_out write.
  unsigned short* X = (unsigned short*)d_out;
  float* outf = (float*)d_out;

  hipMemsetAsync(counts, 0, 65536, stream);
  rank_count<<<dim3(64, 8), 256, 0, stream>>>(imp, counts);
  scatter_order<<<64, 256, 0, stream>>>(counts, order);

  wconv<<<2048, 256, 0, stream>>>(We0T, We0, 512, 1024, 512, 1024);
  wconv<<<448,  256, 0, stream>>>(We1T, We1, 224, 512, 204, 512);
  wconv<<<448,  256, 0, stream>>>(Wd1T, Wd1, 512, 224, 512, 204);
  wconv<<<2048, 256, 0, stream>>>(Wd0T, Wd0, 1024, 512, 1024, 512);

  gather_rows<<<M1ROWS, 256, 0, stream>>>(X, keys, values, order);

  // GEMM1: Y = relu(X @ We0 + be0)   [26216 x 1024] x [1024 x 512]
  gemm_bias_relu<0><<<dim3(205, 4), 256, 0, stream>>>(
      X, M1ROWS, 1024, We0T, 512, be0, 512, Y, 512, nullptr, nullptr);

  // level-0 exact copies (after X consumed)
  copy_level0<<<6552, 256, 0, stream>>>(outf, keys, values, order);

  // GEMM2a: Z = relu(Y_l2 @ We1 + be1)   [22022 x 512] x [512 x 224(pad)]
  gemm_bias_relu<0><<<dim3(173, 2), 256, 0, stream>>>(
      Y + (size_t)L2ROW0 * 512, M2ROWS, 512, We1T, 224, be1, 204, Z, 224, nullptr, nullptr);

  // GEMM2b: Y_l2 = relu(Z @ Wd1 + bd1)   [22022 x 224] x [224 x 512]
  gemm_bias_relu<0><<<dim3(173, 4), 256, 0, stream>>>(
      Z, M2ROWS, 224, Wd1T, 512, bd1, 512, Y + (size_t)L2ROW0 * 512, 512, nullptr, nullptr);

  // GEMM3: out = relu(Y @ Wd0 + bd0), scattered f32  [26216 x 512] x [512 x 1024]
  gemm_bias_relu<1><<<dim3(205, 8), 256, 0, stream>>>(
      Y, M1ROWS, 512, Wd0T, 1024, bd0, 1024, nullptr, 0, outf, order);
}

// Round 3
// 304.187 us; speedup vs baseline: 1.1107x; 1.0877x over previous
//
#include <hip/hip_runtime.h>

typedef __attribute__((ext_vector_type(8))) short short8;
typedef __attribute__((ext_vector_type(4))) float f32x4;

#define N_TOK   16384
#define HDIM    1024
#define OUT_OFF 16777216   // 16384*1024
#define M1ROWS  26216      // 2*(2097+11011)
#define M2ROWS  22022      // 2*11011
#define L2ROW0  4194       // 2*2097

__device__ __forceinline__ unsigned short f2bf(float f) {
  unsigned int u = __float_as_uint(f);
  u += 0x7FFFu + ((u >> 16) & 1u);
  return (unsigned short)(u >> 16);
}

// gathered-row index -> (tensor, rank)
__device__ __forceinline__ void rowmap(int r, int& is_v, int& rank) {
  if (r < 2097)       { is_v = 0; rank = 3276 + r; }
  else if (r < 4194)  { is_v = 1; rank = 1179 + r; }
  else if (r < 15205) { is_v = 0; rank = 1179 + r; }
  else                { is_v = 1; rank = r - 9832; }
}

// ---- stable descending rank: count[i] = #{j : imp[j]>imp[i] or (== and j<i)} ----
__global__ __launch_bounds__(256) void rank_count(const float* __restrict__ imp,
                                                  int* __restrict__ counts) {
  __shared__ float sj[2048];
  const int i = blockIdx.x * 256 + threadIdx.x;
  const int jbase = blockIdx.y * 2048;
  const float vi = imp[i];
  for (int s = threadIdx.x; s < 2048; s += 256) sj[s] = imp[jbase + s];
  __syncthreads();
  int cnt = 0;
  #pragma unroll 8
  for (int s = 0; s < 2048; ++s) {
    float vj = sj[s];
    bool gt = vj > vi;
    bool eq = (vj == vi) && ((jbase + s) < i);
    cnt += (gt || eq) ? 1 : 0;
  }
  atomicAdd(&counts[i], cnt);
}

__global__ __launch_bounds__(256) void scatter_order(const int* __restrict__ counts,
                                                     int* __restrict__ order) {
  int i = blockIdx.x * 256 + threadIdx.x;
  order[counts[i]] = i;
}

// ---- weight convert: dst[N][K] bf16 (transposed, zero-padded) from src[Ksrc][Nsrc] f32 ----
__global__ __launch_bounds__(256) void wconv(unsigned short* __restrict__ dst,
                                             const float* __restrict__ src,
                                             int Nd, int Kd, int Nsrc, int Ksrc) {
  int idx = blockIdx.x * 256 + threadIdx.x;
  if (idx >= Nd * Kd) return;
  int n = idx / Kd, k = idx % Kd;
  float v = (n < Nsrc && k < Ksrc) ? src[k * Nsrc + n] : 0.f;
  dst[idx] = f2bf(v);
}

// ---- gather level>=1 rows into bf16 X ----
__global__ __launch_bounds__(256) void gather_rows(unsigned short* __restrict__ X,
                                                   const float* __restrict__ keys,
                                                   const float* __restrict__ values,
                                                   const int* __restrict__ order) {
  int r = blockIdx.x;
  int is_v, rank; rowmap(r, is_v, rank);
  int token = order[rank];
  const float* src = (is_v ? values : keys) + (size_t)token * HDIM;
  int c = threadIdx.x * 4;
  float4 f = *reinterpret_cast<const float4*>(src + c);
  ushort4 h;
  h.x = f2bf(f.x); h.y = f2bf(f.y); h.z = f2bf(f.z); h.w = f2bf(f.w);
  *reinterpret_cast<ushort4*>(X + (size_t)r * HDIM + c) = h;
}

// ---- level 0: exact f32 passthrough ----
__global__ __launch_bounds__(256) void copy_level0(float* __restrict__ out,
                                                   const float* __restrict__ keys,
                                                   const float* __restrict__ values,
                                                   const int* __restrict__ order) {
  int b = blockIdx.x;
  int is_v = b & 1, rank = b >> 1;
  int token = order[rank];
  const float* src = (is_v ? values : keys) + (size_t)token * HDIM;
  float* dst = out + (is_v ? OUT_OFF : 0) + (size_t)token * HDIM;
  int c = threadIdx.x * 4;
  *reinterpret_cast<float4*>(dst + c) = *reinterpret_cast<const float4*>(src + c);
}

#define GLDS16(g, l) __builtin_amdgcn_global_load_lds( \
    (const __attribute__((address_space(1))) void*)(g), \
    (__attribute__((address_space(3))) void*)(l), 16, 0, 0)

// ---- tiled bf16 GEMM: C = relu(A @ B + bias); B given transposed [N][K] ----
// 3-deep pipeline: loads issued 2 tiles ahead, raw s_barrier + counted
// s_waitcnt vmcnt(4) (never 0 mid-loop) so prefetch stays in flight across
// the barrier. XOR-swizzled LDS (source pre-swizzle + read-side XOR) keeps
// ds_read_b128 conflict-free. XCD-bijective block swizzle: panel p only on
// XCD p%8, so all NC col-blocks of a panel share one L2 (A fetched once).
// MODE 0: store bf16 to Cbf (ldc). MODE 1: scatter f32 to outf via rowmap/order.
template<int MODE>
__global__ __launch_bounds__(256) void gemm_bias_relu(
    const unsigned short* __restrict__ A, int M, int K,
    const unsigned short* __restrict__ Bt, int N,
    const float* __restrict__ bias, int Nbias,
    unsigned short* __restrict__ Cbf, int ldc,
    float* __restrict__ outf, const int* __restrict__ order,
    int NP, int NC) {
  __shared__ __align__(16) unsigned short As[3][128 * 32];
  __shared__ __align__(16) unsigned short Bs[3][128 * 32];
  // XCD swizzle: bid = r + 8*(c + NC*q); panel p = 8q + r -> XCD = bid%8 = p%8
  const int bid = blockIdx.x;
  const int r8 = bid & 7;
  const int rest = bid >> 3;
  const int c8 = rest % NC;
  const int q8 = rest / NC;
  const int p8 = q8 * 8 + r8;
  if (p8 >= NP) return;
  const int row0 = p8 * 128, col0 = c8 * 128;

  const int tid = threadIdx.x;
  const int wave = tid >> 6, lane = tid & 63;
  const int lrow = lane >> 2;
  // source chunk for linear LDS slot (lane&3) of row (lane>>2):
  const int lk = (((lane & 3) ^ ((lane >> 3) & 3)) << 3);
  const int wr = (wave >> 1) * 64, wc = (wave & 1) * 64;

  // staging: 8 segments of 16 rows; wave handles segs {2w, 2w+1} for A and B
  const int s0 = wave * 2, s1 = wave * 2 + 1;
  int ar0 = row0 + s0 * 16 + lrow; if (ar0 >= M) ar0 = 0;
  int ar1 = row0 + s1 * 16 + lrow; if (ar1 >= M) ar1 = 0;
  int br0 = col0 + s0 * 16 + lrow; if (br0 >= N) br0 = 0;
  int br1 = col0 + s1 * 16 + lrow; if (br1 >= N) br1 = 0;
  const unsigned short* ap0 = A + (size_t)ar0 * K + lk;
  const unsigned short* ap1 = A + (size_t)ar1 * K + lk;
  const unsigned short* bp0 = Bt + (size_t)br0 * K + lk;
  const unsigned short* bp1 = Bt + (size_t)br1 * K + lk;

  f32x4 acc[4][4] = {};
  const int fr = lane & 15;
  // read-side swizzle: chunk q=(lane>>4) of row (…+fr) lives at slot q^((fr>>1)&3)
  const int qoff = (((lane >> 4) ^ ((fr >> 1) & 3)) << 3);

  const int nt = K >> 5;
  // prologue: stage tiles 0,1 into bufs 0,1 (8 outstanding loads per wave)
  GLDS16(ap0, As[0] + s0 * 512);
  GLDS16(ap1, As[0] + s1 * 512);
  GLDS16(bp0, Bs[0] + s0 * 512);
  GLDS16(bp1, Bs[0] + s1 * 512);
  GLDS16(ap0 + 32, As[1] + s0 * 512);
  GLDS16(ap1 + 32, As[1] + s1 * 512);
  GLDS16(bp0 + 32, Bs[1] + s0 * 512);
  GLDS16(bp1 + 32, Bs[1] + s1 * 512);

  int cur = 0;
  for (int t = 0; t < nt; ++t) {
    // own tile-t loads done (<=4 outstanding = tile t+1); never drain to 0 mid-loop
    if (t + 1 < nt) asm volatile("s_waitcnt vmcnt(4)" ::: "memory");
    else            asm volatile("s_waitcnt vmcnt(0)" ::: "memory");
    __builtin_amdgcn_s_barrier();          // all waves' tile-t loads landed
    __builtin_amdgcn_sched_barrier(0);
    const unsigned short* as = As[cur];
    const unsigned short* bs = Bs[cur];
    short8 af[4], bfv[4];
    #pragma unroll
    for (int m = 0; m < 4; ++m)
      af[m] = *reinterpret_cast<const short8*>(as + (wr + m * 16 + fr) * 32 + qoff);
    #pragma unroll
    for (int n = 0; n < 4; ++n)
      bfv[n] = *reinterpret_cast<const short8*>(bs + (wc + n * 16 + fr) * 32 + qoff);
    if (t + 2 < nt) {                      // issue 2-ahead into the freed buffer
      const int k2 = (t + 2) << 5;
      int nb = cur + 2; if (nb >= 3) nb -= 3;
      GLDS16(ap0 + k2, As[nb] + s0 * 512);
      GLDS16(ap1 + k2, As[nb] + s1 * 512);
      GLDS16(bp0 + k2, Bs[nb] + s0 * 512);
      GLDS16(bp1 + k2, Bs[nb] + s1 * 512);
    }
    #pragma unroll
    for (int m = 0; m < 4; ++m)
      #pragma unroll
      for (int n = 0; n < 4; ++n)
        acc[m][n] = __builtin_amdgcn_mfma_f32_16x16x32_bf16(af[m], bfv[n], acc[m][n], 0, 0, 0);
    cur = (cur == 2) ? 0 : cur + 1;
  }

  const int orow = (lane >> 4) * 4;
  const int ocol = lane & 15;
  #pragma unroll
  for (int m = 0; m < 4; ++m) {
    #pragma unroll
    for (int n = 0; n < 4; ++n) {
      #pragma unroll
      for (int j = 0; j < 4; ++j) {
        int r = row0 + wr + m * 16 + orow + j;
        int c = col0 + wc + n * 16 + ocol;
        if (r < M && c < N) {
          float v = acc[m][n][j] + (c < Nbias ? bias[c] : 0.f);
          v = fmaxf(v, 0.f);
          if (MODE == 0) {
            Cbf[(size_t)r * ldc + c] = f2bf(v);
          } else {
            int iv, rk; rowmap(r, iv, rk);
            int token = order[rk];
            outf[(size_t)(iv ? OUT_OFF : 0) + (size_t)token * HDIM + c] = v;
          }
        }
      }
    }
  }
}

static inline int swz_grid(int NP, int NC) { return 8 * NC * ((NP + 7) / 8); }

extern "C" void kernel_launch(void* const* d_in, const int* in_sizes, int n_in,
                              void* d_out, int out_size, void* d_ws, size_t ws_size,
                              hipStream_t stream) {
  const float* keys   = (const float*)d_in[0];
  const float* values = (const float*)d_in[1];
  const float* imp    = (const float*)d_in[2];
  const float* We0    = (const float*)d_in[3];
  const float* be0    = (const float*)d_in[4];
  const float* We1    = (const float*)d_in[5];
  const float* be1    = (const float*)d_in[6];
  const float* Wd0    = (const float*)d_in[7];
  const float* bd0    = (const float*)d_in[8];
  const float* Wd1    = (const float*)d_in[9];
  const float* bd1    = (const float*)d_in[10];

  char* ws = (char*)d_ws;
  int* counts           = (int*)(ws);                    // 64 KB
  int* order            = (int*)(ws + 65536);            // 64 KB
  unsigned short* We0T  = (unsigned short*)(ws + 131072);   // [512][1024]
  unsigned short* We1T  = (unsigned short*)(ws + 1179648);  // [224][512]
  unsigned short* Wd1T  = (unsigned short*)(ws + 1409024);  // [512][224]
  unsigned short* Wd0T  = (unsigned short*)(ws + 1638400);  // [1024][512]
  unsigned short* Y     = (unsigned short*)(ws + 2686976);  // [26216][512]
  unsigned short* Z     = (unsigned short*)(ws + 29532160); // [22022][224]
  // X (gathered bf16 inputs) lives in d_out; consumed by GEMM1 before any d_out write.
  unsigned short* X = (unsigned short*)d_out;
  float* outf = (float*)d_out;

  hipMemsetAsync(counts, 0, 65536, stream);
  rank_count<<<dim3(64, 8), 256, 0, stream>>>(imp, counts);
  scatter_order<<<64, 256, 0, stream>>>(counts, order);

  wconv<<<2048, 256, 0, stream>>>(We0T, We0, 512, 1024, 512, 1024);
  wconv<<<448,  256, 0, stream>>>(We1T, We1, 224, 512, 204, 512);
  wconv<<<448,  256, 0, stream>>>(Wd1T, Wd1, 512, 224, 512, 204);
  wconv<<<2048, 256, 0, stream>>>(Wd0T, Wd0, 1024, 512, 1024, 512);

  gather_rows<<<M1ROWS, 256, 0, stream>>>(X, keys, values, order);

  // GEMM1: Y = relu(X @ We0 + be0)   [26216 x 1024] x [1024 x 512]
  gemm_bias_relu<0><<<swz_grid(205, 4), 256, 0, stream>>>(
      X, M1ROWS, 1024, We0T, 512, be0, 512, Y, 512, nullptr, nullptr, 205, 4);

  // level-0 exact copies (after X consumed)
  copy_level0<<<6552, 256, 0, stream>>>(outf, keys, values, order);

  // GEMM2a: Z = relu(Y_l2 @ We1 + be1)   [22022 x 512] x [512 x 224(pad)]
  gemm_bias_relu<0><<<swz_grid(173, 2), 256, 0, stream>>>(
      Y + (size_t)L2ROW0 * 512, M2ROWS, 512, We1T, 224, be1, 204, Z, 224,
      nullptr, nullptr, 173, 2);

  // GEMM2b: Y_l2 = relu(Z @ Wd1 + bd1)   [22022 x 224] x [224 x 512]
  gemm_bias_relu<0><<<swz_grid(173, 4), 256, 0, stream>>>(
      Z, M2ROWS, 224, Wd1T, 512, bd1, 512, Y + (size_t)L2ROW0 * 512, 512,
      nullptr, nullptr, 173, 4);

  // GEMM3: out = relu(Y @ Wd0 + bd0), scattered f32  [26216 x 512] x [512 x 1024]
  gemm_bias_relu<1><<<swz_grid(205, 8), 256, 0, stream>>>(
      Y, M1ROWS, 512, Wd0T, 1024, bd0, 1024, nullptr, 0, outf, order, 205, 8);
}

// Round 4
// 274.393 us; speedup vs baseline: 1.2313x; 1.1086x over previous
//
#include <hip/hip_runtime.h>

typedef __attribute__((ext_vector_type(8))) short short8;
typedef __attribute__((ext_vector_type(4))) float f32x4;

#define N_TOK   16384
#define HDIM    1024
#define OUT_OFF 16777216   // 16384*1024
#define M1ROWS  26216      // 2*(2097+11011)
#define M2ROWS  22022      // 2*11011
#define L2ROW0  4194       // 2*2097

__device__ __forceinline__ unsigned short f2bf(float f) {
  unsigned int u = __float_as_uint(f);
  u += 0x7FFFu + ((u >> 16) & 1u);
  return (unsigned short)(u >> 16);
}

// gathered-row index -> (tensor, rank)
__device__ __forceinline__ void rowmap(int r, int& is_v, int& rank) {
  if (r < 2097)       { is_v = 0; rank = 3276 + r; }
  else if (r < 4194)  { is_v = 1; rank = 1179 + r; }
  else if (r < 15205) { is_v = 0; rank = 1179 + r; }
  else                { is_v = 1; rank = r - 9832; }
}

// ---- stable descending rank: count[i] = #{j : imp[j]>imp[i] or (== and j<i)} ----
__global__ __launch_bounds__(256) void rank_count(const float* __restrict__ imp,
                                                  int* __restrict__ counts) {
  __shared__ float sj[2048];
  const int i = blockIdx.x * 256 + threadIdx.x;
  const int jbase = blockIdx.y * 2048;
  const float vi = imp[i];
  for (int s = threadIdx.x; s < 2048; s += 256) sj[s] = imp[jbase + s];
  __syncthreads();
  int cnt = 0;
  #pragma unroll 8
  for (int s = 0; s < 2048; ++s) {
    float vj = sj[s];
    bool gt = vj > vi;
    bool eq = (vj == vi) && ((jbase + s) < i);
    cnt += (gt || eq) ? 1 : 0;
  }
  atomicAdd(&counts[i], cnt);
}

__global__ __launch_bounds__(256) void scatter_order(const int* __restrict__ counts,
                                                     int* __restrict__ order) {
  int i = blockIdx.x * 256 + threadIdx.x;
  order[counts[i]] = i;
}

// ---- weight convert: dst[N][K] bf16 (transposed, zero-padded) from src[Ksrc][Nsrc] f32 ----
__global__ __launch_bounds__(256) void wconv(unsigned short* __restrict__ dst,
                                             const float* __restrict__ src,
                                             int Nd, int Kd, int Nsrc, int Ksrc) {
  int idx = blockIdx.x * 256 + threadIdx.x;
  if (idx >= Nd * Kd) return;
  int n = idx / Kd, k = idx % Kd;
  float v = (n < Nsrc && k < Ksrc) ? src[k * Nsrc + n] : 0.f;
  dst[idx] = f2bf(v);
}

// ---- gather level>=1 rows into bf16 X ----
__global__ __launch_bounds__(256) void gather_rows(unsigned short* __restrict__ X,
                                                   const float* __restrict__ keys,
                                                   const float* __restrict__ values,
                                                   const int* __restrict__ order) {
  int r = blockIdx.x;
  int is_v, rank; rowmap(r, is_v, rank);
  int token = order[rank];
  const float* src = (is_v ? values : keys) + (size_t)token * HDIM;
  int c = threadIdx.x * 4;
  float4 f = *reinterpret_cast<const float4*>(src + c);
  ushort4 h;
  h.x = f2bf(f.x); h.y = f2bf(f.y); h.z = f2bf(f.z); h.w = f2bf(f.w);
  *reinterpret_cast<ushort4*>(X + (size_t)r * HDIM + c) = h;
}

// ---- level 0: exact f32 passthrough ----
__global__ __launch_bounds__(256) void copy_level0(float* __restrict__ out,
                                                   const float* __restrict__ keys,
                                                   const float* __restrict__ values,
                                                   const int* __restrict__ order) {
  int b = blockIdx.x;
  int is_v = b & 1, rank = b >> 1;
  int token = order[rank];
  const float* src = (is_v ? values : keys) + (size_t)token * HDIM;
  float* dst = out + (is_v ? OUT_OFF : 0) + (size_t)token * HDIM;
  int c = threadIdx.x * 4;
  *reinterpret_cast<float4*>(dst + c) = *reinterpret_cast<const float4*>(src + c);
}

#define GLDS16(g, l) __builtin_amdgcn_global_load_lds( \
    (const __attribute__((address_space(1))) void*)(g), \
    (__attribute__((address_space(3))) void*)(l), 16, 0, 0)

// ---- tiled bf16 GEMM: C = relu(A @ B + bias); B given transposed [N][K] ----
// 256x128 tile, 8 waves: 128 MFMA per block-iteration against one barrier
// (2x payload per K-step vs 128x128). 3-deep pipeline with counted
// s_waitcnt vmcnt(3) (never 0 mid-loop). XOR-swizzled LDS (source
// pre-swizzle + read-side XOR) keeps ds_read_b128 conflict-free.
// XCD-bijective block swizzle: panel p only on XCD p%8.
// LDS superbuffer S[3][(256+128)*32]: A rows 0..255, B rows at +8192.
// MODE 0: store bf16 to Cbf (ldc). MODE 1: scatter f32 to outf via rowmap/order.
template<int MODE>
__global__ __launch_bounds__(512) void gemm_bias_relu(
    const unsigned short* __restrict__ A, int M, int K,
    const unsigned short* __restrict__ Bt, int N,
    const float* __restrict__ bias, int Nbias,
    unsigned short* __restrict__ Cbf, int ldc,
    float* __restrict__ outf, const int* __restrict__ order,
    int NP, int NC) {
  __shared__ __align__(16) unsigned short S[3][12288];
  // XCD swizzle: bid = r + 8*(c + NC*q); panel p = 8q + r -> XCD = bid%8 = p%8
  const int bid = blockIdx.x;
  const int r8 = bid & 7;
  const int rest = bid >> 3;
  const int c8 = rest % NC;
  const int q8 = rest / NC;
  const int p8 = q8 * 8 + r8;
  if (p8 >= NP) return;
  const int row0 = p8 * 256, col0 = c8 * 128;

  const int tid = threadIdx.x;
  const int wave = tid >> 6, lane = tid & 63;
  const int lrow = lane >> 2;
  // source chunk for linear LDS slot (lane&3) of row (lane>>2):
  const int lk = (((lane & 3) ^ ((lane >> 3) & 3)) << 3);
  const int wr = (wave >> 1) * 64, wc = (wave & 1) * 64;

  // staging: 24 segments of 16 rows (A: segs 0..15, B: segs 16..23);
  // wave w handles segs 3w..3w+2 -> 3 global_load_lds per wave per tile
  const unsigned short* gp[3];
  int ldso[3];
  #pragma unroll
  for (int j = 0; j < 3; ++j) {
    const int g = wave * 3 + j;
    const bool isA = g < 16;
    int rr = isA ? (row0 + g * 16 + lrow) : (col0 + (g - 16) * 16 + lrow);
    const int lim = isA ? M : N;
    if (rr >= lim) rr = 0;
    gp[j] = (isA ? A : Bt) + (size_t)rr * K + lk;
    ldso[j] = g * 512;
  }

  f32x4 acc[4][4] = {};
  const int fr = lane & 15;
  // read-side swizzle: chunk q=(lane>>4) of row (…+fr) lives at slot q^((fr>>1)&3)
  const int qoff = (((lane >> 4) ^ ((fr >> 1) & 3)) << 3);

  const int nt = K >> 5;
  // prologue: stage tiles 0,1 into bufs 0,1 (6 outstanding loads per wave)
  #pragma unroll
  for (int j = 0; j < 3; ++j) GLDS16(gp[j], S[0] + ldso[j]);
  #pragma unroll
  for (int j = 0; j < 3; ++j) GLDS16(gp[j] + 32, S[1] + ldso[j]);

  int cur = 0;
  for (int t = 0; t < nt; ++t) {
    // own tile-t loads done (<=3 outstanding = tile t+1); never drain to 0 mid-loop
    if (t + 1 < nt) asm volatile("s_waitcnt vmcnt(3)" ::: "memory");
    else            asm volatile("s_waitcnt vmcnt(0)" ::: "memory");
    __builtin_amdgcn_s_barrier();          // all waves' tile-t loads landed
    __builtin_amdgcn_sched_barrier(0);
    const unsigned short* as = S[cur];
    const unsigned short* bs = S[cur] + 8192;
    short8 af[4], bfv[4];
    #pragma unroll
    for (int m = 0; m < 4; ++m)
      af[m] = *reinterpret_cast<const short8*>(as + (wr + m * 16 + fr) * 32 + qoff);
    #pragma unroll
    for (int n = 0; n < 4; ++n)
      bfv[n] = *reinterpret_cast<const short8*>(bs + (wc + n * 16 + fr) * 32 + qoff);
    if (t + 2 < nt) {                      // issue 2-ahead into the freed buffer
      const int k2 = (t + 2) << 5;
      int nb = cur + 2; if (nb >= 3) nb -= 3;
      #pragma unroll
      for (int j = 0; j < 3; ++j) GLDS16(gp[j] + k2, S[nb] + ldso[j]);
    }
    #pragma unroll
    for (int m = 0; m < 4; ++m)
      #pragma unroll
      for (int n = 0; n < 4; ++n)
        acc[m][n] = __builtin_amdgcn_mfma_f32_16x16x32_bf16(af[m], bfv[n], acc[m][n], 0, 0, 0);
    cur = (cur == 2) ? 0 : cur + 1;
  }

  const int orow = (lane >> 4) * 4;
  const int ocol = lane & 15;
  #pragma unroll
  for (int m = 0; m < 4; ++m) {
    #pragma unroll
    for (int n = 0; n < 4; ++n) {
      #pragma unroll
      for (int j = 0; j < 4; ++j) {
        int r = row0 + wr + m * 16 + orow + j;
        int c = col0 + wc + n * 16 + ocol;
        if (r < M && c < N) {
          float v = acc[m][n][j] + (c < Nbias ? bias[c] : 0.f);
          v = fmaxf(v, 0.f);
          if (MODE == 0) {
            Cbf[(size_t)r * ldc + c] = f2bf(v);
          } else {
            int iv, rk; rowmap(r, iv, rk);
            int token = order[rk];
            outf[(size_t)(iv ? OUT_OFF : 0) + (size_t)token * HDIM + c] = v;
          }
        }
      }
    }
  }
}

static inline int swz_grid(int NP, int NC) { return 8 * NC * ((NP + 7) / 8); }

extern "C" void kernel_launch(void* const* d_in, const int* in_sizes, int n_in,
                              void* d_out, int out_size, void* d_ws, size_t ws_size,
                              hipStream_t stream) {
  const float* keys   = (const float*)d_in[0];
  const float* values = (const float*)d_in[1];
  const float* imp    = (const float*)d_in[2];
  const float* We0    = (const float*)d_in[3];
  const float* be0    = (const float*)d_in[4];
  const float* We1    = (const float*)d_in[5];
  const float* be1    = (const float*)d_in[6];
  const float* Wd0    = (const float*)d_in[7];
  const float* bd0    = (const float*)d_in[8];
  const float* Wd1    = (const float*)d_in[9];
  const float* bd1    = (const float*)d_in[10];

  char* ws = (char*)d_ws;
  int* counts           = (int*)(ws);                    // 64 KB
  int* order            = (int*)(ws + 65536);            // 64 KB
  unsigned short* We0T  = (unsigned short*)(ws + 131072);   // [512][1024]
  unsigned short* We1T  = (unsigned short*)(ws + 1179648);  // [224][512]
  unsigned short* Wd1T  = (unsigned short*)(ws + 1409024);  // [512][224]
  unsigned short* Wd0T  = (unsigned short*)(ws + 1638400);  // [1024][512]
  unsigned short* Y     = (unsigned short*)(ws + 2686976);  // [26216][512]
  unsigned short* Z     = (unsigned short*)(ws + 29532160); // [22022][224]
  // X (gathered bf16 inputs) lives in d_out; consumed by GEMM1 before any d_out write.
  unsigned short* X = (unsigned short*)d_out;
  float* outf = (float*)d_out;

  hipMemsetAsync(counts, 0, 65536, stream);
  rank_count<<<dim3(64, 8), 256, 0, stream>>>(imp, counts);
  scatter_order<<<64, 256, 0, stream>>>(counts, order);

  wconv<<<2048, 256, 0, stream>>>(We0T, We0, 512, 1024, 512, 1024);
  wconv<<<448,  256, 0, stream>>>(We1T, We1, 224, 512, 204, 512);
  wconv<<<448,  256, 0, stream>>>(Wd1T, Wd1, 512, 224, 512, 204);
  wconv<<<2048, 256, 0, stream>>>(Wd0T, Wd0, 1024, 512, 1024, 512);

  gather_rows<<<M1ROWS, 256, 0, stream>>>(X, keys, values, order);

  // GEMM1: Y = relu(X @ We0 + be0)   [26216 x 1024] x [1024 x 512]
  gemm_bias_relu<0><<<swz_grid(103, 4), 512, 0, stream>>>(
      X, M1ROWS, 1024, We0T, 512, be0, 512, Y, 512, nullptr, nullptr, 103, 4);

  // level-0 exact copies (after X consumed)
  copy_level0<<<6552, 256, 0, stream>>>(outf, keys, values, order);

  // GEMM2a: Z = relu(Y_l2 @ We1 + be1)   [22022 x 512] x [512 x 224(pad)]
  gemm_bias_relu<0><<<swz_grid(87, 2), 512, 0, stream>>>(
      Y + (size_t)L2ROW0 * 512, M2ROWS, 512, We1T, 224, be1, 204, Z, 224,
      nullptr, nullptr, 87, 2);

  // GEMM2b: Y_l2 = relu(Z @ Wd1 + bd1)   [22022 x 224] x [224 x 512]
  gemm_bias_relu<0><<<swz_grid(87, 4), 512, 0, stream>>>(
      Z, M2ROWS, 224, Wd1T, 512, bd1, 512, Y + (size_t)L2ROW0 * 512, 512,
      nullptr, nullptr, 87, 4);

  // GEMM3: out = relu(Y @ Wd0 + bd0), scattered f32  [26216 x 512] x [512 x 1024]
  gemm_bias_relu<1><<<swz_grid(103, 8), 512, 0, stream>>>(
      Y, M1ROWS, 512, Wd0T, 1024, bd0, 1024, nullptr, 0, outf, order, 103, 8);
}